// Round 2
// baseline (299.840 us; speedup 1.0000x reference)
//
#include <hip/hip_runtime.h>
#include <hip/hip_cooperative_groups.h>

namespace cg = cooperative_groups;

// StateSpaceLayer: out[b,t,r,c] = sum_{j<=t} A[r]^(t-j) * x[b,j,r,c]
// == linear recurrence out[t] = A[r]*out[t-1] + x[t] along seq.
// Shapes: x (4,512,64,64) f32, A (64,) f32, out (4,512,64,64) f32.
//
// V3: grid-level chunked scan with fully CONTIGUOUS global access.
//   V1/V2 used one block per (b,r): every access was a 256 B segment at a
//   16 KB power-of-2 stride -> ~27% DRAM efficiency (float4 didn't help).
//   Now: grid = 4 batches x 64 time-chunks = 256 blocks (1/CU, co-resident).
//   Each block streams 8 contiguous 16 KB planes (thread k owns float4 at
//   plane offset 4k; r = k>>4), scans locally in registers, publishes its
//   chunk-end state, grid-syncs, Horner-combines prior chunk states with
//   multiplier a^8, fixes up, and streams the result back out.

#define B_     4
#define SEQ_   512
#define D_     64
#define PLANE_ (D_ * D_)          // 4096 floats = 16 KB per timestep
#define PQ_    (PLANE_ / 4)       // 1024 float4 per plane
#define CH_    8                  // timesteps per chunk
#define NCH_   (SEQ_ / CH_)       // 64 chunks
#define NTHR_  1024               // 16 waves
#define GRID_  (B_ * NCH_)        // 256 blocks == 256 CUs

// ---- Variant A: chunk-end states in workspace (1 grid sync) --------------
__global__ __launch_bounds__(NTHR_, 4) void ssm_coop_ws(
    const float* __restrict__ x, const float* __restrict__ A,
    float* __restrict__ out, float* __restrict__ E)
{
    const int blk = blockIdx.x;
    const int bi  = blk >> 6;            // batch
    const int m   = blk & (NCH_ - 1);    // time-chunk id
    const int k   = threadIdx.x;         // float4 slot in plane
    const int r   = k >> 4;              // decay row for this slot

    const float a = fmaxf(A[r], 1e-6f);  // clip like reference (EPS=1e-6)

    const float4* xp = (const float4*)x + (size_t)(bi * SEQ_ + m * CH_) * PQ_ + k;
    float4*       op = (float4*)out     + (size_t)(bi * SEQ_ + m * CH_) * PQ_ + k;

    // Phase 1: local scan, contiguous 16 KB loads per timestep per block.
    float4 loc[CH_];
    float s0 = 0.f, s1 = 0.f, s2 = 0.f, s3 = 0.f;
#pragma unroll
    for (int t = 0; t < CH_; ++t) {
        float4 v = xp[t * PQ_];
        s0 = fmaf(s0, a, v.x);
        s1 = fmaf(s1, a, v.y);
        s2 = fmaf(s2, a, v.z);
        s3 = fmaf(s3, a, v.w);
        loc[t] = make_float4(s0, s1, s2, s3);
    }

    // Publish chunk-end state (16 KB contiguous per block).
    ((float4*)E)[(size_t)(bi * NCH_ + m) * PQ_ + k] = make_float4(s0, s1, s2, s3);

    cg::this_grid().sync();

    // Phase 2: carry = Horner over prior chunk-end states with aL = a^8.
    float a2 = a * a, a4 = a2 * a2, aL = a4 * a4;
    float c0 = 0.f, c1 = 0.f, c2 = 0.f, c3 = 0.f;
    const float4* Eb = (const float4*)E + (size_t)bi * NCH_ * PQ_ + k;
    for (int mp = 0; mp < m; ++mp) {
        float4 e = Eb[(size_t)mp * PQ_];
        c0 = fmaf(c0, aL, e.x);
        c1 = fmaf(c1, aL, e.y);
        c2 = fmaf(c2, aL, e.z);
        c3 = fmaf(c3, aL, e.w);
    }

    // Phase 3: fixup + contiguous stores.  out[j0+t] = loc[t] + carry*a^(t+1)
    float p = a;
#pragma unroll
    for (int t = 0; t < CH_; ++t) {
        float4 l = loc[t];
        op[t * PQ_] = make_float4(fmaf(c0, p, l.x), fmaf(c1, p, l.y),
                                  fmaf(c2, p, l.z), fmaf(c3, p, l.w));
        p *= a;
    }
}

// ---- Variant B: no workspace; chunk-end states parked in out's last plane
//      of each chunk (needs a 2nd grid sync before the corrected overwrite).
__global__ __launch_bounds__(NTHR_, 4) void ssm_coop_planes(
    const float* __restrict__ x, const float* __restrict__ A,
    float* __restrict__ out)
{
    const int blk = blockIdx.x;
    const int bi  = blk >> 6;
    const int m   = blk & (NCH_ - 1);
    const int k   = threadIdx.x;
    const int r   = k >> 4;

    const float a = fmaxf(A[r], 1e-6f);

    const float4* xp = (const float4*)x + (size_t)(bi * SEQ_ + m * CH_) * PQ_ + k;
    float4*       op = (float4*)out     + (size_t)(bi * SEQ_ + m * CH_) * PQ_ + k;

    float4 loc[CH_];
    float s0 = 0.f, s1 = 0.f, s2 = 0.f, s3 = 0.f;
#pragma unroll
    for (int t = 0; t < CH_; ++t) {
        float4 v = xp[t * PQ_];
        s0 = fmaf(s0, a, v.x);
        s1 = fmaf(s1, a, v.y);
        s2 = fmaf(s2, a, v.z);
        s3 = fmaf(s3, a, v.w);
        loc[t] = make_float4(s0, s1, s2, s3);
    }

    // Publish chunk-end state into out[bi, m*CH_+CH_-1, :, :].
    op[(CH_ - 1) * PQ_] = make_float4(s0, s1, s2, s3);

    cg::this_grid().sync();   // all E planes visible

    float a2 = a * a, a4 = a2 * a2, aL = a4 * a4;
    float c0 = 0.f, c1 = 0.f, c2 = 0.f, c3 = 0.f;
    const float4* Eb = (const float4*)out + ((size_t)bi * SEQ_ + (CH_ - 1)) * PQ_ + k;
    for (int mp = 0; mp < m; ++mp) {
        float4 e = Eb[(size_t)mp * CH_ * PQ_];
        c0 = fmaf(c0, aL, e.x);
        c1 = fmaf(c1, aL, e.y);
        c2 = fmaf(c2, aL, e.z);
        c3 = fmaf(c3, aL, e.w);
    }

    cg::this_grid().sync();   // all reads done before corrected overwrite

    float p = a;
#pragma unroll
    for (int t = 0; t < CH_; ++t) {
        float4 l = loc[t];
        op[t * PQ_] = make_float4(fmaf(c0, p, l.x), fmaf(c1, p, l.y),
                                  fmaf(c2, p, l.z), fmaf(c3, p, l.w));
        p *= a;
    }
}

extern "C" void kernel_launch(void* const* d_in, const int* in_sizes, int n_in,
                              void* d_out, int out_size, void* d_ws, size_t ws_size,
                              hipStream_t stream) {
    const float* x   = (const float*)d_in[0];
    const float* A   = (const float*)d_in[1];
    float*       out = (float*)d_out;

    const size_t eBytes = sizeof(float) * (size_t)B_ * NCH_ * PLANE_;  // 4 MB

    if (d_ws != nullptr && ws_size >= eBytes) {
        float* E = (float*)d_ws;
        void* args[] = {(void*)&x, (void*)&A, (void*)&out, (void*)&E};
        hipLaunchCooperativeKernel((void*)ssm_coop_ws, dim3(GRID_), dim3(NTHR_),
                                   args, 0, stream);
    } else {
        void* args[] = {(void*)&x, (void*)&A, (void*)&out};
        hipLaunchCooperativeKernel((void*)ssm_coop_planes, dim3(GRID_), dim3(NTHR_),
                                   args, 0, stream);
    }
}

// Round 3
// 92.654 us; speedup vs baseline: 3.2361x; 3.2361x over previous
//
#include <hip/hip_runtime.h>

// StateSpaceLayer: out[b,t,r,c] = sum_{j<=t} A[r]^(t-j) * x[b,j,r,c]
// == linear recurrence out[t] = A[r]*out[t-1] + x[t] along seq.
// Shapes: x (4,512,64,64) f32, A (64,) f32, out (4,512,64,64) f32.
//
// V4: three stream-ordered kernels (no cooperative launch), all with fully
// CONTIGUOUS global access over time-chunks:
//   K1: per (b, chunk m, half-plane): local scan of 8 timesteps, keep only
//       chunk-end state -> E[b,m,plane]  (4 MB workspace).
//   K2: per (b, float4-slot): 64-step Horner over E with aL=a^8 -> exclusive
//       carries C[b,m,plane] (4 MB workspace). Linear work (V3's in-kernel
//       lookback was quadratic: 129 MB of L2/L3 reads -> 55 us).
//   K3: per (b, chunk m, half-plane): re-read x (L3-warm), scan with initial
//       state C[b,m], store out contiguously.

#define B_     4
#define SEQ_   512
#define D_     64
#define PLANE_ (D_ * D_)          // 4096 floats = 16 KB per timestep
#define PQ_    (PLANE_ / 4)       // 1024 float4 per plane
#define CH_    8                  // timesteps per chunk
#define NCH_   (SEQ_ / CH_)       // 64 chunks
#define SPLIT_ 2                  // half-planes per chunk block
#define THR1_  (PQ_ / SPLIT_)     // 512 threads for K1/K3

// ---- K1: chunk-end state reduce -----------------------------------------
__global__ __launch_bounds__(THR1_) void ssm_k1_reduce(
    const float* __restrict__ x, const float* __restrict__ A,
    float* __restrict__ E)
{
    const int blk = blockIdx.x;               // ((b*NCH + m)*SPLIT + h)
    const int h   = blk & (SPLIT_ - 1);
    const int m   = (blk >> 1) & (NCH_ - 1);
    const int b   = blk >> 7;
    const int k   = h * THR1_ + threadIdx.x;  // float4 slot in plane
    const int r   = k >> 4;

    const float a = fmaxf(A[r], 1e-6f);       // clip like reference (EPS=1e-6)

    const float4* xp = (const float4*)x + (size_t)(b * SEQ_ + m * CH_) * PQ_ + k;

    float s0 = 0.f, s1 = 0.f, s2 = 0.f, s3 = 0.f;
#pragma unroll
    for (int t = 0; t < CH_; ++t) {
        float4 v = xp[t * PQ_];
        s0 = fmaf(s0, a, v.x);
        s1 = fmaf(s1, a, v.y);
        s2 = fmaf(s2, a, v.z);
        s3 = fmaf(s3, a, v.w);
    }
    ((float4*)E)[(size_t)(b * NCH_ + m) * PQ_ + k] = make_float4(s0, s1, s2, s3);
}

// ---- K2: exclusive carry scan over chunks (linear, fully unrolled) ------
__global__ __launch_bounds__(64) void ssm_k2_carry(
    const float* __restrict__ A,
    const float* __restrict__ E, float* __restrict__ C)
{
    const int g = blockIdx.x * 64 + threadIdx.x;   // 0 .. B_*PQ_-1 (4096)
    const int b = g >> 10;
    const int k = g & (PQ_ - 1);
    const int r = k >> 4;

    const float a  = fmaxf(A[r], 1e-6f);
    const float a2 = a * a, a4 = a2 * a2, aL = a4 * a4;   // a^8

    const float4* Eb = (const float4*)E + (size_t)(b * NCH_) * PQ_ + k;
    float4*       Cb = (float4*)C       + (size_t)(b * NCH_) * PQ_ + k;

    float c0 = 0.f, c1 = 0.f, c2 = 0.f, c3 = 0.f;
#pragma unroll
    for (int m = 0; m < NCH_; ++m) {
        Cb[(size_t)m * PQ_] = make_float4(c0, c1, c2, c3);  // exclusive carry
        float4 e = Eb[(size_t)m * PQ_];
        c0 = fmaf(c0, aL, e.x);
        c1 = fmaf(c1, aL, e.y);
        c2 = fmaf(c2, aL, e.z);
        c3 = fmaf(c3, aL, e.w);
    }
}

// ---- K3: recompute local scan with carry init, store out ----------------
__global__ __launch_bounds__(THR1_) void ssm_k3_fixup(
    const float* __restrict__ x, const float* __restrict__ A,
    const float* __restrict__ C, float* __restrict__ out)
{
    const int blk = blockIdx.x;
    const int h   = blk & (SPLIT_ - 1);
    const int m   = (blk >> 1) & (NCH_ - 1);
    const int b   = blk >> 7;
    const int k   = h * THR1_ + threadIdx.x;
    const int r   = k >> 4;

    const float a = fmaxf(A[r], 1e-6f);

    const float4* xp = (const float4*)x + (size_t)(b * SEQ_ + m * CH_) * PQ_ + k;
    float4*       op = (float4*)out     + (size_t)(b * SEQ_ + m * CH_) * PQ_ + k;

    float4 c4 = ((const float4*)C)[(size_t)(b * NCH_ + m) * PQ_ + k];
    float s0 = c4.x, s1 = c4.y, s2 = c4.z, s3 = c4.w;

#pragma unroll
    for (int t = 0; t < CH_; ++t) {
        float4 v = xp[t * PQ_];
        s0 = fmaf(s0, a, v.x);
        s1 = fmaf(s1, a, v.y);
        s2 = fmaf(s2, a, v.z);
        s3 = fmaf(s3, a, v.w);
        op[t * PQ_] = make_float4(s0, s1, s2, s3);
    }
}

// ---- Fallback (ws too small): V1 single-kernel strided scan -------------
#define CHF_ 32
#define NWF_ (SEQ_ / CHF_)
__global__ __launch_bounds__(NWF_ * 64) void ssm_fallback(
    const float* __restrict__ x, const float* __restrict__ A,
    float* __restrict__ out)
{
    __shared__ float Elds[NWF_ * D_];
    const int blk = blockIdx.x, bi = blk >> 6, r = blk & 63;
    const int tid = threadIdx.x, w = tid >> 6, c = tid & 63;
    const float a = fmaxf(A[r], 1e-6f);
    const size_t base = ((size_t)(bi * SEQ_ + w * CHF_) * D_ + r) * D_ + c;
    const float* xp = x + base;
    float*       op = out + base;
    const int js = D_ * D_;
    float local[CHF_];
    float state = 0.0f;
#pragma unroll
    for (int t = 0; t < CHF_; ++t) {
        state = fmaf(state, a, xp[(size_t)t * js]);
        local[t] = state;
    }
    Elds[w * D_ + c] = state;
    __syncthreads();
    float aL = a * a; aL *= aL; aL *= aL; aL *= aL; aL *= aL;  // a^32
    float carry = 0.0f;
    for (int wp = 0; wp < w; ++wp) carry = fmaf(carry, aL, Elds[wp * D_ + c]);
    float p = a;
#pragma unroll
    for (int t = 0; t < CHF_; ++t) {
        op[(size_t)t * js] = fmaf(carry, p, local[t]);
        p *= a;
    }
}

extern "C" void kernel_launch(void* const* d_in, const int* in_sizes, int n_in,
                              void* d_out, int out_size, void* d_ws, size_t ws_size,
                              hipStream_t stream) {
    const float* x   = (const float*)d_in[0];
    const float* A   = (const float*)d_in[1];
    float*       out = (float*)d_out;

    const size_t planeBytes = sizeof(float) * (size_t)B_ * NCH_ * PLANE_;  // 4 MB

    if (d_ws != nullptr && ws_size >= 2 * planeBytes) {
        float* E = (float*)d_ws;
        float* C = (float*)d_ws + (size_t)B_ * NCH_ * PLANE_;

        hipLaunchKernelGGL(ssm_k1_reduce, dim3(B_ * NCH_ * SPLIT_), dim3(THR1_),
                           0, stream, x, A, E);
        hipLaunchKernelGGL(ssm_k2_carry, dim3(B_ * PQ_ / 64), dim3(64),
                           0, stream, A, E, C);
        hipLaunchKernelGGL(ssm_k3_fixup, dim3(B_ * NCH_ * SPLIT_), dim3(THR1_),
                           0, stream, x, A, C, out);
    } else {
        hipLaunchKernelGGL(ssm_fallback, dim3(B_ * D_), dim3(NWF_ * 64),
                           0, stream, x, A, out);
    }
}